// Round 7
// baseline (503.445 us; speedup 1.0000x reference)
//
#include <hip/hip_runtime.h>
#include <hip/hip_bf16.h>
#include <math.h>

#define D_MODEL 1024
#define DD (1024 * 1024)

typedef unsigned short ushort_t;
using short8 = __attribute__((ext_vector_type(8))) short;   // 8 bf16 (4 VGPRs)
using f32x4  = __attribute__((ext_vector_type(4))) float;   // 4 fp32 acc

#define ACT_NONE 0
#define ACT_SILU 1

__device__ __forceinline__ float bf2f(ushort_t u) {
    return __uint_as_float(((unsigned int)u) << 16);
}
__device__ __forceinline__ ushort_t f2bf(float f) {
    unsigned int x = __float_as_uint(f);
    x += 0x7fffu + ((x >> 16) & 1u);   // round-to-nearest-even
    return (ushort_t)(x >> 16);
}

#define GL2LDS(gp, lp)                                                         \
    __builtin_amdgcn_global_load_lds(                                          \
        (const __attribute__((address_space(1))) void*)(gp),                   \
        (__attribute__((address_space(3))) void*)(lp), 16, 0, 0)

// ---------------------------------------------------------------------------
// 256x256-tile bf16 GEMM — R2 structure VERBATIM (session-best 43.8us/GEMM,
// 0 bank conflicts): one-phase-ahead register prefetch, counted lgkm waits,
// ring-4 LDS unit buffers, 1 barrier/phase.  K-loop untouched since R2.
// Template'd epilogue extensions (GEMM5/6 use STATS=LNAFF=0, R2-identical):
//   STATS: per-row Sum/SumSq of (v+bias) reduced via shfl over the 16-lane
//          col group, one atomicAdd pair per row-fragment -> stats[row].
//   LNAFF: apply LayerNorm-affine  v -> r*v - r*mu*csw[col] + bias[col]
//          (exact identity: LN(q)@W = r*(q@W) - r*mu*colsum(W)), then ACT.
// stats/csw live in the UPPER HALF of d_out (dead until the final GEMM) —
// d_ws footprint identical to the R1-R4 passing rounds.
// ---------------------------------------------------------------------------
template <int ACT, int OUTF32, int BIASF, int STATS, int LNAFF>
__global__ __launch_bounds__(512, 2) void gemm256(
    const ushort_t* __restrict__ A,
    const ushort_t* __restrict__ Bt,
    const float* __restrict__ bias,
    void* __restrict__ Cv, int M,
    float* __restrict__ stats, const float* __restrict__ csw)
{
    constexpr int K = 1024, N = 1024;
    constexpr int NU = K / 32;                 // 32 K-units
    __shared__ ushort_t lds[4 * 16384];        // 128 KiB: 4 x (A 8192 + B 8192)

    const int tid  = threadIdx.x;
    const int lane = tid & 63;
    const int wave = tid >> 6;                 // 0..7
    const int quad = lane >> 4;
    const int lr   = lane & 15;
    const int wm   = wave >> 2;                // 0..1  (M-wave)
    const int wn   = wave & 3;                 // 0..3  (N-wave)
    const int bm   = blockIdx.x;
    const int bn   = blockIdx.y;

    const ushort_t* Ab = A  + (size_t)bm * 256 * K;
    const ushort_t* Bb = Bt + (size_t)bn * 256 * K;

    // staging: thread t writes LDS bytes [t*16, t*16+16) (+8192 for row+128)
    const int sg    = (tid & 3) ^ ((tid >> 3) & 3);   // inverse k-chunk swizzle
    const size_t s0 = (size_t)(tid >> 2) * K + (size_t)sg * 8;
    const size_t s1 = s0 + (size_t)128 * K;
    const int d0 = tid * 8;
    const int d1 = tid * 8 + 4096;

    // ds_read lane offsets (ushorts); chunk-XOR matches the staged swizzle
    const int chk  = quad ^ ((lr >> 1) & 3);
    const int aoff = (wm * 128 + lr) * 32 + chk * 8;
    const int boff = (wn * 64  + lr) * 32 + chk * 8;

    short8 bfr[4], afrE[4], afrO[4];
    f32x4 acc[8][4];
#pragma unroll
    for (int i = 0; i < 8; i++)
#pragma unroll
        for (int j = 0; j < 4; j++) acc[i][j] = (f32x4){0.f, 0.f, 0.f, 0.f};

#define SA(v) do { const int b_ = ((v) & 3) * 16384;                           \
        GL2LDS(Ab + s0 + (v) * 32, lds + b_ + d0);                             \
        GL2LDS(Ab + s1 + (v) * 32, lds + b_ + d1); } while (0)
#define SB(v) do { const int b_ = ((v) & 3) * 16384 + 8192;                    \
        GL2LDS(Bb + s0 + (v) * 32, lds + b_ + d0);                             \
        GL2LDS(Bb + s1 + (v) * 32, lds + b_ + d1); } while (0)
#define RAE(v) do { const ushort_t* p_ = lds + ((v) & 3) * 16384 + aoff;       \
        afrE[0] = *(const short8*)(p_);                                        \
        afrE[1] = *(const short8*)(p_ + 512);                                  \
        afrE[2] = *(const short8*)(p_ + 1024);                                 \
        afrE[3] = *(const short8*)(p_ + 1536); } while (0)
#define RAO(v) do { const ushort_t* p_ = lds + ((v) & 3) * 16384 + aoff + 2048;\
        afrO[0] = *(const short8*)(p_);                                        \
        afrO[1] = *(const short8*)(p_ + 512);                                  \
        afrO[2] = *(const short8*)(p_ + 1024);                                 \
        afrO[3] = *(const short8*)(p_ + 1536); } while (0)
#define RB(v) do { const ushort_t* p_ = lds + ((v) & 3) * 16384 + 8192 + boff; \
        bfr[0] = *(const short8*)(p_);                                         \
        bfr[1] = *(const short8*)(p_ + 512);                                   \
        bfr[2] = *(const short8*)(p_ + 1024);                                  \
        bfr[3] = *(const short8*)(p_ + 1536); } while (0)

    // prologue: stage units 0,1,2 (12 loads); drain unit 0; first frag reads.
    SA(0); SB(0);
    SA(1); SB(1);
    SA(2); SB(2);
    asm volatile("s_waitcnt vmcnt(8)" ::: "memory");
    __builtin_amdgcn_s_barrier();
    RAE(0);
    RB(0);
    __builtin_amdgcn_sched_barrier(0);   // pin issue order before loop's RAO

#pragma unroll
    for (int u = 0; u < NU; ++u) {
        // ---------------- even phase (2u) ----------------
        RAO(u);                                   // prefetch for odd phase
        asm volatile("s_waitcnt vmcnt(4)" ::: "memory");
        __builtin_amdgcn_s_barrier();
        if (u + 3 < NU) SA(u + 3);
        asm volatile("s_waitcnt lgkmcnt(4)" ::: "memory");  // afrE,bfr ready
        __builtin_amdgcn_sched_barrier(0);
        __builtin_amdgcn_s_setprio(1);
#pragma unroll
        for (int mt = 0; mt < 4; mt++)
#pragma unroll
            for (int nt = 0; nt < 4; nt++)
                acc[mt][nt] = __builtin_amdgcn_mfma_f32_16x16x32_bf16(
                    afrE[mt], bfr[nt], acc[mt][nt], 0, 0, 0);
        __builtin_amdgcn_s_setprio(0);
        // ---------------- odd phase (2u+1) ----------------
        if (u + 1 < NU) RAE(u + 1);               // prefetch for next even
        asm volatile("s_waitcnt vmcnt(4)" ::: "memory");
        __builtin_amdgcn_s_barrier();
        if (u + 3 < NU) SB(u + 3);
        if (u + 1 < NU)
            asm volatile("s_waitcnt lgkmcnt(4)" ::: "memory"); // afrO ready
        else
            asm volatile("s_waitcnt lgkmcnt(0)" ::: "memory");
        __builtin_amdgcn_sched_barrier(0);
        __builtin_amdgcn_s_setprio(1);
#pragma unroll
        for (int mt = 0; mt < 4; mt++)
#pragma unroll
            for (int nt = 0; nt < 4; nt++)
                acc[mt + 4][nt] = __builtin_amdgcn_mfma_f32_16x16x32_bf16(
                    afrO[mt], bfr[nt], acc[mt + 4][nt], 0, 0, 0);
        __builtin_amdgcn_s_setprio(0);
        if (u + 1 < NU) {
            RB(u + 1);                            // late bfr prefetch
            __builtin_amdgcn_sched_barrier(0);    // keep before next RAO
        }
    }
#undef SA
#undef SB
#undef RAE
#undef RAO
#undef RB

    // ------------------------- epilogue -------------------------
    float bv[4], cw[4];
#pragma unroll
    for (int nt = 0; nt < 4; nt++) {
        const int col = bn * 256 + wn * 64 + nt * 16 + lr;
        bv[nt] = BIASF ? bias[col] : 0.f;
        cw[nt] = LNAFF ? csw[col] : 0.f;
    }

#pragma unroll
    for (int mt = 0; mt < 8; mt++) {
#pragma unroll
        for (int r = 0; r < 4; r++) {
            const int row = bm * 256 + wm * 128 + mt * 16 + quad * 4 + r;
            float rin = 1.f, rmu = 0.f;
            if (LNAFF) {
                const float2 st = *(const float2*)(stats + 2 * (size_t)row);
                const float mu  = st.x * (1.f / D_MODEL);
                const float var = st.y * (1.f / D_MODEL) - mu * mu;
                rin = rsqrtf(var + 1e-5f);
                rmu = rin * mu;
            }
            float s4 = 0.f, ss4 = 0.f;
#pragma unroll
            for (int nt = 0; nt < 4; nt++) {
                const int col = bn * 256 + wn * 64 + nt * 16 + lr;
                float v = acc[mt][nt][r];
                if (LNAFF) v = rin * v - rmu * cw[nt] + bv[nt];
                else       v = v + bv[nt];
                if (STATS) { s4 += v; ss4 += v * v; }
                if (ACT == ACT_SILU) v = v / (1.f + __expf(-v));
                if (OUTF32)
                    ((float*)Cv)[(size_t)row * N + col] = v;
                else
                    ((ushort_t*)Cv)[(size_t)row * N + col] = f2bf(v);
            }
            if (STATS) {
                // reduce over the 16-lane lr group (stays within quad)
#pragma unroll
                for (int m_ = 1; m_ < 16; m_ <<= 1) {
                    s4  += __shfl_xor(s4,  m_);
                    ss4 += __shfl_xor(ss4, m_);
                }
                if (lr == 0) {
                    atomicAdd(stats + 2 * (size_t)row,     s4);
                    atomicAdd(stats + 2 * (size_t)row + 1, ss4);
                }
            }
        }
    }
}

// ---------------------------------------------------------------------------
// bf16 GEMM — R2 128x128 structure (kept for the small 1024^3 Wf GEMM and as
// fallback when M % 256 != 0).
// ---------------------------------------------------------------------------
template <int ACT, int OUTF32, int BIASF>
__global__ __launch_bounds__(256) void gemm_bf16(
    const ushort_t* __restrict__ A,
    const ushort_t* __restrict__ Bt,
    const float* __restrict__ bias,
    void* __restrict__ Cv, int M)
{
    constexpr int K = 1024, N = 1024;
    __shared__ ushort_t As[128 * 32];
    __shared__ ushort_t Bs[128 * 32];

    const int tid  = threadIdx.x;
    const int lane = tid & 63;
    const int wave = tid >> 6;
    const int quad = lane >> 4;
    const int lr   = lane & 15;
    const int bm   = blockIdx.x;
    const int bn   = blockIdx.y;
    const int wm   = (wave >> 1) * 64;
    const int wn   = (wave & 1) * 64;

    f32x4 acc[4][4];
#pragma unroll
    for (int i = 0; i < 4; i++)
#pragma unroll
        for (int j = 0; j < 4; j++) acc[i][j] = (f32x4){0.f, 0.f, 0.f, 0.f};

    int ci0 = tid, ci1 = tid + 256;
    int am0 = ci0 >> 2, akc0 = (ci0 & 3) ^ ((am0 >> 1) & 3);
    int am1 = ci1 >> 2, akc1 = (ci1 & 3) ^ ((am1 >> 1) & 3);
    const ushort_t* Ab = A + (size_t)(bm * 128) * K;
    const ushort_t* Bb = Bt + (size_t)(bn * 128) * K;

    for (int k0 = 0; k0 < K; k0 += 32) {
        GL2LDS(Ab + (size_t)am0 * K + k0 + akc0 * 8, As + ci0 * 8);
        GL2LDS(Ab + (size_t)am1 * K + k0 + akc1 * 8, As + ci1 * 8);
        GL2LDS(Bb + (size_t)am0 * K + k0 + akc0 * 8, Bs + ci0 * 8);
        GL2LDS(Bb + (size_t)am1 * K + k0 + akc1 * 8, Bs + ci1 * 8);
        __syncthreads();

        short8 af[4], bfr[4];
#pragma unroll
        for (int t = 0; t < 4; t++) {
            int m = wm + t * 16 + lr;
            af[t] = *(const short8*)(As + m * 32 + ((quad ^ ((m >> 1) & 3)) * 8));
            int n = wn + t * 16 + lr;
            bfr[t] = *(const short8*)(Bs + n * 32 + ((quad ^ ((n >> 1) & 3)) * 8));
        }
#pragma unroll
        for (int mt = 0; mt < 4; mt++)
#pragma unroll
            for (int nt = 0; nt < 4; nt++)
                acc[mt][nt] = __builtin_amdgcn_mfma_f32_16x16x32_bf16(
                    af[mt], bfr[nt], acc[mt][nt], 0, 0, 0);
        __syncthreads();
    }

    float bv[4];
#pragma unroll
    for (int nt = 0; nt < 4; nt++)
        bv[nt] = BIASF ? bias[bn * 128 + wn + nt * 16 + lr] : 0.f;

#pragma unroll
    for (int mt = 0; mt < 4; mt++) {
#pragma unroll
        for (int nt = 0; nt < 4; nt++) {
            const int col = bn * 128 + wn + nt * 16 + lr;
#pragma unroll
            for (int r = 0; r < 4; r++) {
                const int row = bm * 128 + wm + mt * 16 + quad * 4 + r;
                float v = acc[mt][nt][r] + bv[nt];
                if (ACT == ACT_SILU) v = v / (1.f + __expf(-v));
                if (OUTF32)
                    ((float*)Cv)[(size_t)row * N + col] = v;
                else
                    ((ushort_t*)Cv)[(size_t)row * N + col] = f2bf(v);
            }
        }
    }
}

// ---------------------------------------------------------------------------
// In-place LayerNorm over bf16 rows of 1024 (fallback path only).
// ---------------------------------------------------------------------------
__global__ __launch_bounds__(256) void layernorm_bf16(ushort_t* __restrict__ X)
{
    const int row = blockIdx.x;
    const int tid = threadIdx.x;
    ushort_t* x = X + (size_t)row * D_MODEL + tid * 4;

    uint2 u = *(uint2*)x;
    float a = bf2f(u.x & 0xffff), b = bf2f(u.x >> 16);
    float c = bf2f(u.y & 0xffff), d = bf2f(u.y >> 16);
    float s = a + b + c + d;
    float ss = a * a + b * b + c * c + d * d;

#pragma unroll
    for (int off = 32; off > 0; off >>= 1) {
        s += __shfl_down(s, off);
        ss += __shfl_down(ss, off);
    }
    __shared__ float sbuf[4], ssbuf[4];
    const int wave = tid >> 6;
    if ((tid & 63) == 0) { sbuf[wave] = s; ssbuf[wave] = ss; }
    __syncthreads();
    const float S = sbuf[0] + sbuf[1] + sbuf[2] + sbuf[3];
    const float SS = ssbuf[0] + ssbuf[1] + ssbuf[2] + ssbuf[3];
    const float mu = S * (1.f / D_MODEL);
    const float var = SS * (1.f / D_MODEL) - mu * mu;
    const float r = rsqrtf(var + 1e-5f);

    a = (a - mu) * r; b = (b - mu) * r; c = (c - mu) * r; d = (d - mu) * r;
    u.x = (unsigned)f2bf(a) | ((unsigned)f2bf(b) << 16);
    u.y = (unsigned)f2bf(c) | ((unsigned)f2bf(d) << 16);
    *(uint2*)x = u;
}

// ---------------------------------------------------------------------------
// ONE prep dispatch (flattened 1-D grid):
//  [0,6144):      weight prep (transpose/convert), 6 z-slices
//  [6144,+nxblk): x fp32 -> bf16
//  then 32 blocks bias_compose, 32 blocks csw0 (colsum of mlp_w[0]),
//  32 blocks zero-stats.
// ---------------------------------------------------------------------------
__global__ __launch_bounds__(256) void prep_all(
    const float* __restrict__ wq, const float* __restrict__ mlp_w,
    const float* __restrict__ w_out, const float* __restrict__ x,
    const float* __restrict__ b3, const float* __restrict__ bout,
    ushort_t* __restrict__ wt, ushort_t* __restrict__ Q,
    float* __restrict__ bf, float* __restrict__ stats,
    float* __restrict__ csw, int nxblk)
{
    const int blk = blockIdx.x;
    const int tid = threadIdx.x;

    if (blk < 6144) {                    // ---- weight prep ----
        const int z = blk >> 10;
        const int t = blk & 1023;        // 32x32 tile index
        const int k0 = (t >> 5) * 32;
        const int n0 = (t & 31) * 32;
        const int r = tid >> 5;          // 0..7
        const int c = tid & 31;          // 0..31

        if (z == 5) {                    // plain convert W3
            const float* src = mlp_w + (size_t)3 * DD;
            ushort_t* dst = wt + (size_t)5 * DD;
#pragma unroll
            for (int i = 0; i < 4; i++) {
                size_t idx = (size_t)(k0 + r + 8 * i) * D_MODEL + n0 + c;
                dst[idx] = f2bf(src[idx]);
            }
            return;
        }
        const float* src = (z == 0) ? wq : (z < 4) ? (mlp_w + (size_t)(z - 1) * DD) : w_out;
        ushort_t* dst = wt + (size_t)z * DD;
        __shared__ float tile[32][33];
#pragma unroll
        for (int i = 0; i < 4; i++)
            tile[r + 8 * i][c] = src[(size_t)(k0 + r + 8 * i) * D_MODEL + n0 + c];
        __syncthreads();
#pragma unroll
        for (int i = 0; i < 4; i++)
            dst[(size_t)(n0 + r + 8 * i) * D_MODEL + k0 + c] = f2bf(tile[c][r + 8 * i]);
        return;
    }
    if (blk < 6144 + nxblk) {            // ---- x -> bf16 ----
        int i = (blk - 6144) * 256 + tid;
        const float4* p = (const float4*)(x + (size_t)i * 8);
        float4 v0 = p[0], v1 = p[1];
        union { ushort_t u[8]; uint4 v; } pk;
        pk.u[0] = f2bf(v0.x); pk.u[1] = f2bf(v0.y);
        pk.u[2] = f2bf(v0.z); pk.u[3] = f2bf(v0.w);
        pk.u[4] = f2bf(v1.x); pk.u[5] = f2bf(v1.y);
        pk.u[6] = f2bf(v1.z); pk.u[7] = f2bf(v1.w);
        *(uint4*)(Q + (size_t)i * 8) = pk.v;
        return;
    }
    const int t = blk - 6144 - nxblk;
    if (t < 32) {
        // ---- bias_compose: bf[n] = b3 @ Wout + bout, split-K 8-way ----
        const int n = t * 32 + (tid & 31);
        const int kg = tid >> 5;                 // 0..7
        float s = 0.f;
        for (int k = kg * 128; k < (kg + 1) * 128; k++)
            s = fmaf(b3[k], w_out[(size_t)k * D_MODEL + n], s);
        __shared__ float red[8][32];
        red[kg][tid & 31] = s;
        __syncthreads();
        if (kg == 0) {
            float tt = 0.f;
#pragma unroll
            for (int j = 0; j < 8; j++) tt += red[j][tid & 31];
            bf[n] = tt + bout[n];
        }
        return;
    }
    if (t < 64) {
        // ---- csw0[n] = colsum of mlp_w[0], split-K 8-way ----
        const int b = t - 32;
        const int n = b * 32 + (tid & 31);
        const int kg = tid >> 5;
        float s = 0.f;
        for (int k = kg * 128; k < (kg + 1) * 128; k++)
            s += mlp_w[(size_t)k * D_MODEL + n];
        __shared__ float red2[8][32];
        red2[kg][tid & 31] = s;
        __syncthreads();
        if (kg == 0) {
            float tt = 0.f;
#pragma unroll
            for (int j = 0; j < 8; j++) tt += red2[j][tid & 31];
            csw[n] = tt;
        }
        return;
    }
    {   // ---- zero stats: 32 blocks x 256 threads x 4 floats = 32768 ----
        const int b = t - 64;
        *(float4*)(stats + (size_t)b * 1024 + tid * 4) =
            (float4){0.f, 0.f, 0.f, 0.f};
    }
}

// ---------------------------------------------------------------------------
extern "C" void kernel_launch(void* const* d_in, const int* in_sizes, int n_in,
                              void* d_out, int out_size, void* d_ws, size_t ws_size,
                              hipStream_t stream)
{
    const float* x     = (const float*)d_in[0];
    const float* wq    = (const float*)d_in[1];
    const float* bq    = (const float*)d_in[2];
    const float* mlp_w = (const float*)d_in[3];
    const float* mlp_b = (const float*)d_in[4];
    const float* w_out = (const float*)d_in[5];
    const float* b_out = (const float*)d_in[6];

    const int D = D_MODEL;
    const int M = in_sizes[0] / D;   // 16384

    // ws layout (ushort units) — IDENTICAL footprint to R1-R4 passing rounds:
    // wt[0..5)=transposed weights | [5DD,6DD)=W3 plain | [6DD,7DD)=WfT
    // | Q (M*D) | bf (1024 f32)
    ushort_t* wt    = (ushort_t*)d_ws;
    ushort_t* w3b   = wt + (size_t)5 * DD;
    ushort_t* wtF   = wt + (size_t)6 * DD;
    ushort_t* Q     = wt + (size_t)7 * DD;
    float*    bf    = (float*)(Q + (size_t)M * D);
    ushort_t* P     = (ushort_t*)d_out;   // bf16 acts alias d_out LOWER half
    // stats (2*M f32) + csw (1024 f32) live in d_out's UPPER half (bytes
    // [32MB,64MB)) — dead until the final GEMM overwrites all of d_out.
    float*    ob    = (float*)d_out;
    float*    stats = ob + (size_t)M * D / 2;          // float offset 8M
    float*    csw   = stats + 2 * (size_t)M;

    // 1. all prep in one dispatch (+csw colsum, +stats zeroing)
    const int nxblk = M * D / 2048;     // x-convert blocks (8 elems/thread)
    prep_all<<<6144 + nxblk + 96, 256, 0, stream>>>(
        wq, mlp_w, w_out, x, mlp_b + 3 * D, b_out, wt, Q, bf, stats, csw, nxblk);
    // 2. Wf^T = Wout^T @ W3^T  (N-major rep of Wf = W3*Wout) — small GEMM
    gemm_bf16<ACT_NONE, 0, 0><<<dim3(8, 8), 256, 0, stream>>>(
        wt + (size_t)4 * DD, w3b, nullptr, wtF, 1024);

    if ((M & 255) == 0) {
        dim3 grid(M / 256, D / 256);    // 64 x 4 = 256 blocks = 1/CU
        // 3. q = x @ wq + bq -> P (raw, un-normalized) + row stats via atomics
        gemm256<ACT_NONE, 0, 1, 1, 0><<<grid, 512, 0, stream>>>(
            Q, wt + (size_t)0 * DD, bq, P, M, stats, nullptr);
        // 4. layer0 fused with LN-affine:  h0 = silu(r*(q@W0) - r*mu*csW0 + b0)
        gemm256<ACT_SILU, 0, 1, 0, 1><<<grid, 512, 0, stream>>>(
            P, wt + (size_t)1 * DD, mlp_b + 0 * D, Q, M, stats, csw);
        // 5-6. MLP layers 1..2 with SiLU (unchanged controls)
        gemm256<ACT_SILU, 0, 1, 0, 0><<<grid, 512, 0, stream>>>(
            Q, wt + (size_t)2 * DD, mlp_b + 1 * D, P, M, nullptr, nullptr);
        gemm256<ACT_SILU, 0, 1, 0, 0><<<grid, 512, 0, stream>>>(
            P, wt + (size_t)3 * DD, mlp_b + 2 * D, Q, M, nullptr, nullptr);
        // 7. fused (layer3 + out proj): out = h3 @ Wf + bf -> d_out fp32
        //    (reads Q in ws; overwrites P and the stats scratch — both dead)
        gemm256<ACT_NONE, 1, 1, 0, 0><<<grid, 512, 0, stream>>>(
            Q, wtF, bf, d_out, M, nullptr, nullptr);
    } else {
        dim3 grid(M / 128, D / 128);
        gemm_bf16<ACT_NONE, 0, 1><<<grid, 256, 0, stream>>>(Q, wt + (size_t)0 * DD, bq, P, M);
        layernorm_bf16<<<M, 256, 0, stream>>>(P);
        gemm_bf16<ACT_SILU, 0, 1><<<grid, 256, 0, stream>>>(P, wt + (size_t)1 * DD, mlp_b + 0 * D, Q, M);
        gemm_bf16<ACT_SILU, 0, 1><<<grid, 256, 0, stream>>>(Q, wt + (size_t)2 * DD, mlp_b + 1 * D, P, M);
        gemm_bf16<ACT_SILU, 0, 1><<<grid, 256, 0, stream>>>(P, wt + (size_t)3 * DD, mlp_b + 2 * D, Q, M);
        gemm_bf16<ACT_NONE, 1, 1><<<grid, 256, 0, stream>>>(Q, wtF, bf, d_out, M);
    }
}

// Round 8
// 366.085 us; speedup vs baseline: 1.3752x; 1.3752x over previous
//
#include <hip/hip_runtime.h>
#include <hip/hip_bf16.h>
#include <math.h>

#define D_MODEL 1024
#define DD (1024 * 1024)

typedef unsigned short ushort_t;
using short8 = __attribute__((ext_vector_type(8))) short;   // 8 bf16 (4 VGPRs)
using f32x4  = __attribute__((ext_vector_type(4))) float;   // 4 fp32 acc

#define ACT_NONE 0
#define ACT_SILU 1

__device__ __forceinline__ float bf2f(ushort_t u) {
    return __uint_as_float(((unsigned int)u) << 16);
}
__device__ __forceinline__ ushort_t f2bf(float f) {
    unsigned int x = __float_as_uint(f);
    x += 0x7fffu + ((x >> 16) & 1u);   // round-to-nearest-even
    return (ushort_t)(x >> 16);
}

#define GL2LDS(gp, lp)                                                         \
    __builtin_amdgcn_global_load_lds(                                          \
        (const __attribute__((address_space(1))) void*)(gp),                   \
        (__attribute__((address_space(3))) void*)(lp), 16, 0, 0)

// ---------------------------------------------------------------------------
// 256x256-tile bf16 GEMM — R2 structure VERBATIM (session-best 43.8us/GEMM,
// 0 bank conflicts): one-phase-ahead register prefetch, counted lgkm waits,
// ring-4 LDS unit buffers, 1 barrier/phase.  K-loop untouched since R2.
// Template'd epilogue extensions (GEMM5/6/7 use STATS=LNAFF=0, R2-identical —
// these serve as ENVIRONMENT CONTROLS: measured 43.8us healthy / 98us on the
// degraded R7 node with identical counters):
//   STATS: per-row Sum/SumSq of (v+bias) reduced via shfl over the 16-lane
//          col group, one atomicAdd pair per row-fragment -> stats[row].
//   LNAFF: apply LayerNorm-affine  v -> r*v - r*mu*csw[col] + bias[col]
//          (exact identity: LN(q)@W = r*(q@W) - r*mu*colsum(W)), then ACT.
// stats/csw live in the UPPER HALF of d_out (dead until the final GEMM) —
// d_ws footprint identical to the R1-R4 passing rounds.
// ---------------------------------------------------------------------------
template <int ACT, int OUTF32, int BIASF, int STATS, int LNAFF>
__global__ __launch_bounds__(512, 2) void gemm256(
    const ushort_t* __restrict__ A,
    const ushort_t* __restrict__ Bt,
    const float* __restrict__ bias,
    void* __restrict__ Cv, int M,
    float* __restrict__ stats, const float* __restrict__ csw)
{
    constexpr int K = 1024, N = 1024;
    constexpr int NU = K / 32;                 // 32 K-units
    __shared__ ushort_t lds[4 * 16384];        // 128 KiB: 4 x (A 8192 + B 8192)

    const int tid  = threadIdx.x;
    const int lane = tid & 63;
    const int wave = tid >> 6;                 // 0..7
    const int quad = lane >> 4;
    const int lr   = lane & 15;
    const int wm   = wave >> 2;                // 0..1  (M-wave)
    const int wn   = wave & 3;                 // 0..3  (N-wave)
    const int bm   = blockIdx.x;
    const int bn   = blockIdx.y;

    const ushort_t* Ab = A  + (size_t)bm * 256 * K;
    const ushort_t* Bb = Bt + (size_t)bn * 256 * K;

    // staging: thread t writes LDS bytes [t*16, t*16+16) (+8192 for row+128)
    const int sg    = (tid & 3) ^ ((tid >> 3) & 3);   // inverse k-chunk swizzle
    const size_t s0 = (size_t)(tid >> 2) * K + (size_t)sg * 8;
    const size_t s1 = s0 + (size_t)128 * K;
    const int d0 = tid * 8;
    const int d1 = tid * 8 + 4096;

    // ds_read lane offsets (ushorts); chunk-XOR matches the staged swizzle
    const int chk  = quad ^ ((lr >> 1) & 3);
    const int aoff = (wm * 128 + lr) * 32 + chk * 8;
    const int boff = (wn * 64  + lr) * 32 + chk * 8;

    short8 bfr[4], afrE[4], afrO[4];
    f32x4 acc[8][4];
#pragma unroll
    for (int i = 0; i < 8; i++)
#pragma unroll
        for (int j = 0; j < 4; j++) acc[i][j] = (f32x4){0.f, 0.f, 0.f, 0.f};

#define SA(v) do { const int b_ = ((v) & 3) * 16384;                           \
        GL2LDS(Ab + s0 + (v) * 32, lds + b_ + d0);                             \
        GL2LDS(Ab + s1 + (v) * 32, lds + b_ + d1); } while (0)
#define SB(v) do { const int b_ = ((v) & 3) * 16384 + 8192;                    \
        GL2LDS(Bb + s0 + (v) * 32, lds + b_ + d0);                             \
        GL2LDS(Bb + s1 + (v) * 32, lds + b_ + d1); } while (0)
#define RAE(v) do { const ushort_t* p_ = lds + ((v) & 3) * 16384 + aoff;       \
        afrE[0] = *(const short8*)(p_);                                        \
        afrE[1] = *(const short8*)(p_ + 512);                                  \
        afrE[2] = *(const short8*)(p_ + 1024);                                 \
        afrE[3] = *(const short8*)(p_ + 1536); } while (0)
#define RAO(v) do { const ushort_t* p_ = lds + ((v) & 3) * 16384 + aoff + 2048;\
        afrO[0] = *(const short8*)(p_);                                        \
        afrO[1] = *(const short8*)(p_ + 512);                                  \
        afrO[2] = *(const short8*)(p_ + 1024);                                 \
        afrO[3] = *(const short8*)(p_ + 1536); } while (0)
#define RB(v) do { const ushort_t* p_ = lds + ((v) & 3) * 16384 + 8192 + boff; \
        bfr[0] = *(const short8*)(p_);                                         \
        bfr[1] = *(const short8*)(p_ + 512);                                   \
        bfr[2] = *(const short8*)(p_ + 1024);                                  \
        bfr[3] = *(const short8*)(p_ + 1536); } while (0)

    // prologue: stage units 0,1,2 (12 loads); drain unit 0; first frag reads.
    SA(0); SB(0);
    SA(1); SB(1);
    SA(2); SB(2);
    asm volatile("s_waitcnt vmcnt(8)" ::: "memory");
    __builtin_amdgcn_s_barrier();
    RAE(0);
    RB(0);
    __builtin_amdgcn_sched_barrier(0);   // pin issue order before loop's RAO

#pragma unroll
    for (int u = 0; u < NU; ++u) {
        // ---------------- even phase (2u) ----------------
        RAO(u);                                   // prefetch for odd phase
        asm volatile("s_waitcnt vmcnt(4)" ::: "memory");
        __builtin_amdgcn_s_barrier();
        if (u + 3 < NU) SA(u + 3);
        asm volatile("s_waitcnt lgkmcnt(4)" ::: "memory");  // afrE,bfr ready
        __builtin_amdgcn_sched_barrier(0);
        __builtin_amdgcn_s_setprio(1);
#pragma unroll
        for (int mt = 0; mt < 4; mt++)
#pragma unroll
            for (int nt = 0; nt < 4; nt++)
                acc[mt][nt] = __builtin_amdgcn_mfma_f32_16x16x32_bf16(
                    afrE[mt], bfr[nt], acc[mt][nt], 0, 0, 0);
        __builtin_amdgcn_s_setprio(0);
        // ---------------- odd phase (2u+1) ----------------
        if (u + 1 < NU) RAE(u + 1);               // prefetch for next even
        asm volatile("s_waitcnt vmcnt(4)" ::: "memory");
        __builtin_amdgcn_s_barrier();
        if (u + 3 < NU) SB(u + 3);
        if (u + 1 < NU)
            asm volatile("s_waitcnt lgkmcnt(4)" ::: "memory"); // afrO ready
        else
            asm volatile("s_waitcnt lgkmcnt(0)" ::: "memory");
        __builtin_amdgcn_sched_barrier(0);
        __builtin_amdgcn_s_setprio(1);
#pragma unroll
        for (int mt = 0; mt < 4; mt++)
#pragma unroll
            for (int nt = 0; nt < 4; nt++)
                acc[mt + 4][nt] = __builtin_amdgcn_mfma_f32_16x16x32_bf16(
                    afrO[mt], bfr[nt], acc[mt + 4][nt], 0, 0, 0);
        __builtin_amdgcn_s_setprio(0);
        if (u + 1 < NU) {
            RB(u + 1);                            // late bfr prefetch
            __builtin_amdgcn_sched_barrier(0);    // keep before next RAO
        }
    }
#undef SA
#undef SB
#undef RAE
#undef RAO
#undef RB

    // ------------------------- epilogue -------------------------
    float bv[4], cw[4];
#pragma unroll
    for (int nt = 0; nt < 4; nt++) {
        const int col = bn * 256 + wn * 64 + nt * 16 + lr;
        bv[nt] = BIASF ? bias[col] : 0.f;
        cw[nt] = LNAFF ? csw[col] : 0.f;
    }

#pragma unroll
    for (int mt = 0; mt < 8; mt++) {
#pragma unroll
        for (int r = 0; r < 4; r++) {
            const int row = bm * 256 + wm * 128 + mt * 16 + quad * 4 + r;
            float rin = 1.f, rmu = 0.f;
            if (LNAFF) {
                const float2 st = *(const float2*)(stats + 2 * (size_t)row);
                const float mu  = st.x * (1.f / D_MODEL);
                const float var = st.y * (1.f / D_MODEL) - mu * mu;
                rin = rsqrtf(var + 1e-5f);
                rmu = rin * mu;
            }
            float s4 = 0.f, ss4 = 0.f;
#pragma unroll
            for (int nt = 0; nt < 4; nt++) {
                const int col = bn * 256 + wn * 64 + nt * 16 + lr;
                float v = acc[mt][nt][r];
                if (LNAFF) v = rin * v - rmu * cw[nt] + bv[nt];
                else       v = v + bv[nt];
                if (STATS) { s4 += v; ss4 += v * v; }
                if (ACT == ACT_SILU) v = v / (1.f + __expf(-v));
                if (OUTF32)
                    ((float*)Cv)[(size_t)row * N + col] = v;
                else
                    ((ushort_t*)Cv)[(size_t)row * N + col] = f2bf(v);
            }
            if (STATS) {
                // reduce over the 16-lane lr group (stays within quad)
#pragma unroll
                for (int m_ = 1; m_ < 16; m_ <<= 1) {
                    s4  += __shfl_xor(s4,  m_);
                    ss4 += __shfl_xor(ss4, m_);
                }
                if (lr == 0) {
                    atomicAdd(stats + 2 * (size_t)row,     s4);
                    atomicAdd(stats + 2 * (size_t)row + 1, ss4);
                }
            }
        }
    }
}

// ---------------------------------------------------------------------------
// bf16 GEMM — R2 128x128 structure (kept for the small 1024^3 Wf GEMM and as
// fallback when M % 256 != 0).
// ---------------------------------------------------------------------------
template <int ACT, int OUTF32, int BIASF>
__global__ __launch_bounds__(256) void gemm_bf16(
    const ushort_t* __restrict__ A,
    const ushort_t* __restrict__ Bt,
    const float* __restrict__ bias,
    void* __restrict__ Cv, int M)
{
    constexpr int K = 1024, N = 1024;
    __shared__ ushort_t As[128 * 32];
    __shared__ ushort_t Bs[128 * 32];

    const int tid  = threadIdx.x;
    const int lane = tid & 63;
    const int wave = tid >> 6;
    const int quad = lane >> 4;
    const int lr   = lane & 15;
    const int bm   = blockIdx.x;
    const int bn   = blockIdx.y;
    const int wm   = (wave >> 1) * 64;
    const int wn   = (wave & 1) * 64;

    f32x4 acc[4][4];
#pragma unroll
    for (int i = 0; i < 4; i++)
#pragma unroll
        for (int j = 0; j < 4; j++) acc[i][j] = (f32x4){0.f, 0.f, 0.f, 0.f};

    int ci0 = tid, ci1 = tid + 256;
    int am0 = ci0 >> 2, akc0 = (ci0 & 3) ^ ((am0 >> 1) & 3);
    int am1 = ci1 >> 2, akc1 = (ci1 & 3) ^ ((am1 >> 1) & 3);
    const ushort_t* Ab = A + (size_t)(bm * 128) * K;
    const ushort_t* Bb = Bt + (size_t)(bn * 128) * K;

    for (int k0 = 0; k0 < K; k0 += 32) {
        GL2LDS(Ab + (size_t)am0 * K + k0 + akc0 * 8, As + ci0 * 8);
        GL2LDS(Ab + (size_t)am1 * K + k0 + akc1 * 8, As + ci1 * 8);
        GL2LDS(Bb + (size_t)am0 * K + k0 + akc0 * 8, Bs + ci0 * 8);
        GL2LDS(Bb + (size_t)am1 * K + k0 + akc1 * 8, Bs + ci1 * 8);
        __syncthreads();

        short8 af[4], bfr[4];
#pragma unroll
        for (int t = 0; t < 4; t++) {
            int m = wm + t * 16 + lr;
            af[t] = *(const short8*)(As + m * 32 + ((quad ^ ((m >> 1) & 3)) * 8));
            int n = wn + t * 16 + lr;
            bfr[t] = *(const short8*)(Bs + n * 32 + ((quad ^ ((n >> 1) & 3)) * 8));
        }
#pragma unroll
        for (int mt = 0; mt < 4; mt++)
#pragma unroll
            for (int nt = 0; nt < 4; nt++)
                acc[mt][nt] = __builtin_amdgcn_mfma_f32_16x16x32_bf16(
                    af[mt], bfr[nt], acc[mt][nt], 0, 0, 0);
        __syncthreads();
    }

    float bv[4];
#pragma unroll
    for (int nt = 0; nt < 4; nt++)
        bv[nt] = BIASF ? bias[bn * 128 + wn + nt * 16 + lr] : 0.f;

#pragma unroll
    for (int mt = 0; mt < 4; mt++) {
#pragma unroll
        for (int nt = 0; nt < 4; nt++) {
            const int col = bn * 128 + wn + nt * 16 + lr;
#pragma unroll
            for (int r = 0; r < 4; r++) {
                const int row = bm * 128 + wm + mt * 16 + quad * 4 + r;
                float v = acc[mt][nt][r] + bv[nt];
                if (ACT == ACT_SILU) v = v / (1.f + __expf(-v));
                if (OUTF32)
                    ((float*)Cv)[(size_t)row * N + col] = v;
                else
                    ((ushort_t*)Cv)[(size_t)row * N + col] = f2bf(v);
            }
        }
    }
}

// ---------------------------------------------------------------------------
// In-place LayerNorm over bf16 rows of 1024 (fallback path only).
// ---------------------------------------------------------------------------
__global__ __launch_bounds__(256) void layernorm_bf16(ushort_t* __restrict__ X)
{
    const int row = blockIdx.x;
    const int tid = threadIdx.x;
    ushort_t* x = X + (size_t)row * D_MODEL + tid * 4;

    uint2 u = *(uint2*)x;
    float a = bf2f(u.x & 0xffff), b = bf2f(u.x >> 16);
    float c = bf2f(u.y & 0xffff), d = bf2f(u.y >> 16);
    float s = a + b + c + d;
    float ss = a * a + b * b + c * c + d * d;

#pragma unroll
    for (int off = 32; off > 0; off >>= 1) {
        s += __shfl_down(s, off);
        ss += __shfl_down(ss, off);
    }
    __shared__ float sbuf[4], ssbuf[4];
    const int wave = tid >> 6;
    if ((tid & 63) == 0) { sbuf[wave] = s; ssbuf[wave] = ss; }
    __syncthreads();
    const float S = sbuf[0] + sbuf[1] + sbuf[2] + sbuf[3];
    const float SS = ssbuf[0] + ssbuf[1] + ssbuf[2] + ssbuf[3];
    const float mu = S * (1.f / D_MODEL);
    const float var = SS * (1.f / D_MODEL) - mu * mu;
    const float r = rsqrtf(var + 1e-5f);

    a = (a - mu) * r; b = (b - mu) * r; c = (c - mu) * r; d = (d - mu) * r;
    u.x = (unsigned)f2bf(a) | ((unsigned)f2bf(b) << 16);
    u.y = (unsigned)f2bf(c) | ((unsigned)f2bf(d) << 16);
    *(uint2*)x = u;
}

// ---------------------------------------------------------------------------
// ONE prep dispatch (flattened 1-D grid):
//  [0,6144):      weight prep (transpose/convert), 6 z-slices
//  [6144,+nxblk): x fp32 -> bf16
//  then 32 blocks bias_compose, 32 blocks csw0 (colsum of mlp_w[0]),
//  32 blocks zero-stats.
// ---------------------------------------------------------------------------
__global__ __launch_bounds__(256) void prep_all(
    const float* __restrict__ wq, const float* __restrict__ mlp_w,
    const float* __restrict__ w_out, const float* __restrict__ x,
    const float* __restrict__ b3, const float* __restrict__ bout,
    ushort_t* __restrict__ wt, ushort_t* __restrict__ Q,
    float* __restrict__ bf, float* __restrict__ stats,
    float* __restrict__ csw, int nxblk)
{
    const int blk = blockIdx.x;
    const int tid = threadIdx.x;

    if (blk < 6144) {                    // ---- weight prep ----
        const int z = blk >> 10;
        const int t = blk & 1023;        // 32x32 tile index
        const int k0 = (t >> 5) * 32;
        const int n0 = (t & 31) * 32;
        const int r = tid >> 5;          // 0..7
        const int c = tid & 31;          // 0..31

        if (z == 5) {                    // plain convert W3
            const float* src = mlp_w + (size_t)3 * DD;
            ushort_t* dst = wt + (size_t)5 * DD;
#pragma unroll
            for (int i = 0; i < 4; i++) {
                size_t idx = (size_t)(k0 + r + 8 * i) * D_MODEL + n0 + c;
                dst[idx] = f2bf(src[idx]);
            }
            return;
        }
        const float* src = (z == 0) ? wq : (z < 4) ? (mlp_w + (size_t)(z - 1) * DD) : w_out;
        ushort_t* dst = wt + (size_t)z * DD;
        __shared__ float tile[32][33];
#pragma unroll
        for (int i = 0; i < 4; i++)
            tile[r + 8 * i][c] = src[(size_t)(k0 + r + 8 * i) * D_MODEL + n0 + c];
        __syncthreads();
#pragma unroll
        for (int i = 0; i < 4; i++)
            dst[(size_t)(n0 + r + 8 * i) * D_MODEL + k0 + c] = f2bf(tile[c][r + 8 * i]);
        return;
    }
    if (blk < 6144 + nxblk) {            // ---- x -> bf16 ----
        int i = (blk - 6144) * 256 + tid;
        const float4* p = (const float4*)(x + (size_t)i * 8);
        float4 v0 = p[0], v1 = p[1];
        union { ushort_t u[8]; uint4 v; } pk;
        pk.u[0] = f2bf(v0.x); pk.u[1] = f2bf(v0.y);
        pk.u[2] = f2bf(v0.z); pk.u[3] = f2bf(v0.w);
        pk.u[4] = f2bf(v1.x); pk.u[5] = f2bf(v1.y);
        pk.u[6] = f2bf(v1.z); pk.u[7] = f2bf(v1.w);
        *(uint4*)(Q + (size_t)i * 8) = pk.v;
        return;
    }
    const int t = blk - 6144 - nxblk;
    if (t < 32) {
        // ---- bias_compose: bf[n] = b3 @ Wout + bout, split-K 8-way ----
        const int n = t * 32 + (tid & 31);
        const int kg = tid >> 5;                 // 0..7
        float s = 0.f;
        for (int k = kg * 128; k < (kg + 1) * 128; k++)
            s = fmaf(b3[k], w_out[(size_t)k * D_MODEL + n], s);
        __shared__ float red[8][32];
        red[kg][tid & 31] = s;
        __syncthreads();
        if (kg == 0) {
            float tt = 0.f;
#pragma unroll
            for (int j = 0; j < 8; j++) tt += red[j][tid & 31];
            bf[n] = tt + bout[n];
        }
        return;
    }
    if (t < 64) {
        // ---- csw0[n] = colsum of mlp_w[0], split-K 8-way ----
        const int b = t - 32;
        const int n = b * 32 + (tid & 31);
        const int kg = tid >> 5;
        float s = 0.f;
        for (int k = kg * 128; k < (kg + 1) * 128; k++)
            s += mlp_w[(size_t)k * D_MODEL + n];
        __shared__ float red2[8][32];
        red2[kg][tid & 31] = s;
        __syncthreads();
        if (kg == 0) {
            float tt = 0.f;
#pragma unroll
            for (int j = 0; j < 8; j++) tt += red2[j][tid & 31];
            csw[n] = tt;
        }
        return;
    }
    {   // ---- zero stats: 32 blocks x 256 threads x 4 floats = 32768 ----
        const int b = t - 64;
        *(float4*)(stats + (size_t)b * 1024 + tid * 4) =
            (float4){0.f, 0.f, 0.f, 0.f};
    }
}

// ---------------------------------------------------------------------------
extern "C" void kernel_launch(void* const* d_in, const int* in_sizes, int n_in,
                              void* d_out, int out_size, void* d_ws, size_t ws_size,
                              hipStream_t stream)
{
    const float* x     = (const float*)d_in[0];
    const float* wq    = (const float*)d_in[1];
    const float* bq    = (const float*)d_in[2];
    const float* mlp_w = (const float*)d_in[3];
    const float* mlp_b = (const float*)d_in[4];
    const float* w_out = (const float*)d_in[5];
    const float* b_out = (const float*)d_in[6];

    const int D = D_MODEL;
    const int M = in_sizes[0] / D;   // 16384

    // ws layout (ushort units) — IDENTICAL footprint to R1-R4 passing rounds:
    // wt[0..5)=transposed weights | [5DD,6DD)=W3 plain | [6DD,7DD)=WfT
    // | Q (M*D) | bf (1024 f32)
    ushort_t* wt    = (ushort_t*)d_ws;
    ushort_t* w3b   = wt + (size_t)5 * DD;
    ushort_t* wtF   = wt + (size_t)6 * DD;
    ushort_t* Q     = wt + (size_t)7 * DD;
    float*    bf    = (float*)(Q + (size_t)M * D);
    ushort_t* P     = (ushort_t*)d_out;   // bf16 acts alias d_out LOWER half
    // stats (2*M f32) + csw (1024 f32) live in d_out's UPPER half (bytes
    // [32MB,64MB)) — dead until the final GEMM overwrites all of d_out.
    float*    ob    = (float*)d_out;
    float*    stats = ob + (size_t)M * D / 2;          // float offset 8M
    float*    csw   = stats + 2 * (size_t)M;

    // 1. all prep in one dispatch (+csw colsum, +stats zeroing)
    const int nxblk = M * D / 2048;     // x-convert blocks (8 elems/thread)
    prep_all<<<6144 + nxblk + 96, 256, 0, stream>>>(
        wq, mlp_w, w_out, x, mlp_b + 3 * D, b_out, wt, Q, bf, stats, csw, nxblk);
    // 2. Wf^T = Wout^T @ W3^T  (N-major rep of Wf = W3*Wout) — small GEMM
    gemm_bf16<ACT_NONE, 0, 0><<<dim3(8, 8), 256, 0, stream>>>(
        wt + (size_t)4 * DD, w3b, nullptr, wtF, 1024);

    if ((M & 255) == 0) {
        dim3 grid(M / 256, D / 256);    // 64 x 4 = 256 blocks = 1/CU
        // 3. q = x @ wq + bq -> P (raw, un-normalized) + row stats via atomics
        gemm256<ACT_NONE, 0, 1, 1, 0><<<grid, 512, 0, stream>>>(
            Q, wt + (size_t)0 * DD, bq, P, M, stats, nullptr);
        // 4. layer0 fused with LN-affine:  h0 = silu(r*(q@W0) - r*mu*csW0 + b0)
        gemm256<ACT_SILU, 0, 1, 0, 1><<<grid, 512, 0, stream>>>(
            P, wt + (size_t)1 * DD, mlp_b + 0 * D, Q, M, stats, csw);
        // 5-6. MLP layers 1..2 with SiLU (unchanged controls)
        gemm256<ACT_SILU, 0, 1, 0, 0><<<grid, 512, 0, stream>>>(
            Q, wt + (size_t)2 * DD, mlp_b + 1 * D, P, M, nullptr, nullptr);
        gemm256<ACT_SILU, 0, 1, 0, 0><<<grid, 512, 0, stream>>>(
            P, wt + (size_t)3 * DD, mlp_b + 2 * D, Q, M, nullptr, nullptr);
        // 7. fused (layer3 + out proj): out = h3 @ Wf + bf -> d_out fp32
        //    (reads Q in ws; overwrites P and the stats scratch — both dead)
        gemm256<ACT_NONE, 1, 1, 0, 0><<<grid, 512, 0, stream>>>(
            Q, wtF, bf, d_out, M, nullptr, nullptr);
    } else {
        dim3 grid(M / 128, D / 128);
        gemm_bf16<ACT_NONE, 0, 1><<<grid, 256, 0, stream>>>(Q, wt + (size_t)0 * DD, bq, P, M);
        layernorm_bf16<<<M, 256, 0, stream>>>(P);
        gemm_bf16<ACT_SILU, 0, 1><<<grid, 256, 0, stream>>>(P, wt + (size_t)1 * DD, mlp_b + 0 * D, Q, M);
        gemm_bf16<ACT_SILU, 0, 1><<<grid, 256, 0, stream>>>(Q, wt + (size_t)2 * DD, mlp_b + 1 * D, P, M);
        gemm_bf16<ACT_SILU, 0, 1><<<grid, 256, 0, stream>>>(P, wt + (size_t)3 * DD, mlp_b + 2 * D, Q, M);
        gemm_bf16<ACT_NONE, 1, 1><<<grid, 256, 0, stream>>>(Q, wtF, bf, d_out, M);
    }
}

// Round 10
// 357.382 us; speedup vs baseline: 1.4087x; 1.0244x over previous
//
#include <hip/hip_runtime.h>
#include <hip/hip_bf16.h>
#include <math.h>

#define D_MODEL 1024
#define DD (1024 * 1024)

typedef unsigned short ushort_t;
using short8 = __attribute__((ext_vector_type(8))) short;   // 8 bf16 (4 VGPRs)
using f32x4  = __attribute__((ext_vector_type(4))) float;   // 4 fp32 acc

#define ACT_NONE 0
#define ACT_SILU 1

__device__ __forceinline__ float bf2f(ushort_t u) {
    return __uint_as_float(((unsigned int)u) << 16);
}
__device__ __forceinline__ ushort_t f2bf(float f) {
    unsigned int x = __float_as_uint(f);
    x += 0x7fffu + ((x >> 16) & 1u);   // round-to-nearest-even
    return (ushort_t)(x >> 16);
}

#define GL2LDS(gp, lp)                                                         \
    __builtin_amdgcn_global_load_lds(                                          \
        (const __attribute__((address_space(1))) void*)(gp),                   \
        (__attribute__((address_space(3))) void*)(lp), 16, 0, 0)

// ---------------------------------------------------------------------------
// 256x256-tile bf16 GEMM — R2 K-loop VERBATIM (session-best 43.8us/GEMM,
// 0 bank conflicts).  Epilogue extensions (GEMM5/6/7 use STATS=LNAFF=0,
// R2-identical — environment controls):
//   STATS (v2, no atomics): per-row Sum/SumSq partials combined in LDS
//     (safe: one barrier after the K-loop guarantees all waves drained
//     their ds_reads; scratch sits at LDS offset 0 = ring slot 0, whose
//     staging completed ~30 phases earlier).  One coalesced float2 per
//     (row, bn) -> statsP[row][bn], written exactly once (no init pass).
//     R8 measured the atomic version at +16MB WRITE_SIZE and +4us.
//   LNAFF: v -> r*v - r*mu*csw[col] + bias[col] (exact identity:
//     LN(q)@W = r*(q@W) - r*mu*colsum(W)), reading the 4 bn-partials
//     per row as two float4 from L2.
// statsP/csw live in the UPPER HALF of d_out (dead until the final GEMM
// rewrites all 64MB) — layout validated by R7/R8 passing runs.
// ---------------------------------------------------------------------------
template <int ACT, int OUTF32, int BIASF, int STATS, int LNAFF>
__global__ __launch_bounds__(512, 2) void gemm256(
    const ushort_t* __restrict__ A,
    const ushort_t* __restrict__ Bt,
    const float* __restrict__ bias,
    void* __restrict__ Cv, int M,
    float* __restrict__ stats, const float* __restrict__ csw)
{
    constexpr int K = 1024, N = 1024;
    constexpr int NU = K / 32;                 // 32 K-units
    __shared__ ushort_t lds[4 * 16384];        // 128 KiB: 4 x (A 8192 + B 8192)

    const int tid  = threadIdx.x;
    const int lane = tid & 63;
    const int wave = tid >> 6;                 // 0..7
    const int quad = lane >> 4;
    const int lr   = lane & 15;
    const int wm   = wave >> 2;                // 0..1  (M-wave)
    const int wn   = wave & 3;                 // 0..3  (N-wave)
    const int bm   = blockIdx.x;
    const int bn   = blockIdx.y;

    const ushort_t* Ab = A  + (size_t)bm * 256 * K;
    const ushort_t* Bb = Bt + (size_t)bn * 256 * K;

    // staging: thread t writes LDS bytes [t*16, t*16+16) (+8192 for row+128)
    const int sg    = (tid & 3) ^ ((tid >> 3) & 3);   // inverse k-chunk swizzle
    const size_t s0 = (size_t)(tid >> 2) * K + (size_t)sg * 8;
    const size_t s1 = s0 + (size_t)128 * K;
    const int d0 = tid * 8;
    const int d1 = tid * 8 + 4096;

    // ds_read lane offsets (ushorts); chunk-XOR matches the staged swizzle
    const int chk  = quad ^ ((lr >> 1) & 3);
    const int aoff = (wm * 128 + lr) * 32 + chk * 8;
    const int boff = (wn * 64  + lr) * 32 + chk * 8;

    short8 bfr[4], afrE[4], afrO[4];
    f32x4 acc[8][4];
#pragma unroll
    for (int i = 0; i < 8; i++)
#pragma unroll
        for (int j = 0; j < 4; j++) acc[i][j] = (f32x4){0.f, 0.f, 0.f, 0.f};

#define SA(v) do { const int b_ = ((v) & 3) * 16384;                           \
        GL2LDS(Ab + s0 + (v) * 32, lds + b_ + d0);                             \
        GL2LDS(Ab + s1 + (v) * 32, lds + b_ + d1); } while (0)
#define SB(v) do { const int b_ = ((v) & 3) * 16384 + 8192;                    \
        GL2LDS(Bb + s0 + (v) * 32, lds + b_ + d0);                             \
        GL2LDS(Bb + s1 + (v) * 32, lds + b_ + d1); } while (0)
#define RAE(v) do { const ushort_t* p_ = lds + ((v) & 3) * 16384 + aoff;       \
        afrE[0] = *(const short8*)(p_);                                        \
        afrE[1] = *(const short8*)(p_ + 512);                                  \
        afrE[2] = *(const short8*)(p_ + 1024);                                 \
        afrE[3] = *(const short8*)(p_ + 1536); } while (0)
#define RAO(v) do { const ushort_t* p_ = lds + ((v) & 3) * 16384 + aoff + 2048;\
        afrO[0] = *(const short8*)(p_);                                        \
        afrO[1] = *(const short8*)(p_ + 512);                                  \
        afrO[2] = *(const short8*)(p_ + 1024);                                 \
        afrO[3] = *(const short8*)(p_ + 1536); } while (0)
#define RB(v) do { const ushort_t* p_ = lds + ((v) & 3) * 16384 + 8192 + boff; \
        bfr[0] = *(const short8*)(p_);                                         \
        bfr[1] = *(const short8*)(p_ + 512);                                   \
        bfr[2] = *(const short8*)(p_ + 1024);                                  \
        bfr[3] = *(const short8*)(p_ + 1536); } while (0)

    // prologue: stage units 0,1,2 (12 loads); drain unit 0; first frag reads.
    SA(0); SB(0);
    SA(1); SB(1);
    SA(2); SB(2);
    asm volatile("s_waitcnt vmcnt(8)" ::: "memory");
    __builtin_amdgcn_s_barrier();
    RAE(0);
    RB(0);
    __builtin_amdgcn_sched_barrier(0);   // pin issue order before loop's RAO

#pragma unroll
    for (int u = 0; u < NU; ++u) {
        // ---------------- even phase (2u) ----------------
        RAO(u);                                   // prefetch for odd phase
        asm volatile("s_waitcnt vmcnt(4)" ::: "memory");
        __builtin_amdgcn_s_barrier();
        if (u + 3 < NU) SA(u + 3);
        asm volatile("s_waitcnt lgkmcnt(4)" ::: "memory");  // afrE,bfr ready
        __builtin_amdgcn_sched_barrier(0);
        __builtin_amdgcn_s_setprio(1);
#pragma unroll
        for (int mt = 0; mt < 4; mt++)
#pragma unroll
            for (int nt = 0; nt < 4; nt++)
                acc[mt][nt] = __builtin_amdgcn_mfma_f32_16x16x32_bf16(
                    afrE[mt], bfr[nt], acc[mt][nt], 0, 0, 0);
        __builtin_amdgcn_s_setprio(0);
        // ---------------- odd phase (2u+1) ----------------
        if (u + 1 < NU) RAE(u + 1);               // prefetch for next even
        asm volatile("s_waitcnt vmcnt(4)" ::: "memory");
        __builtin_amdgcn_s_barrier();
        if (u + 3 < NU) SB(u + 3);
        if (u + 1 < NU)
            asm volatile("s_waitcnt lgkmcnt(4)" ::: "memory"); // afrO ready
        else
            asm volatile("s_waitcnt lgkmcnt(0)" ::: "memory");
        __builtin_amdgcn_sched_barrier(0);
        __builtin_amdgcn_s_setprio(1);
#pragma unroll
        for (int mt = 0; mt < 4; mt++)
#pragma unroll
            for (int nt = 0; nt < 4; nt++)
                acc[mt + 4][nt] = __builtin_amdgcn_mfma_f32_16x16x32_bf16(
                    afrO[mt], bfr[nt], acc[mt + 4][nt], 0, 0, 0);
        __builtin_amdgcn_s_setprio(0);
        if (u + 1 < NU) {
            RB(u + 1);                            // late bfr prefetch
            __builtin_amdgcn_sched_barrier(0);    // keep before next RAO
        }
    }
#undef SA
#undef SB
#undef RAE
#undef RAO
#undef RB

    // ------------------------- epilogue -------------------------
    // STATS scratch: [256 rows][4 wn][2] floats = 8 KB at LDS offset 0.
    float* smem = (float*)lds;
    if (STATS) __syncthreads();   // all waves past their final lgkm(0):
                                  // every K-loop ds_read drained -> LDS free

    float bv[4], cw[4];
#pragma unroll
    for (int nt = 0; nt < 4; nt++) {
        const int col = bn * 256 + wn * 64 + nt * 16 + lr;
        bv[nt] = BIASF ? bias[col] : 0.f;
        cw[nt] = LNAFF ? csw[col] : 0.f;
    }

#pragma unroll
    for (int mt = 0; mt < 8; mt++) {
#pragma unroll
        for (int r = 0; r < 4; r++) {
            const int rowl = wm * 128 + mt * 16 + quad * 4 + r;
            const int row  = bm * 256 + rowl;
            float rin = 1.f, rmu = 0.f;
            if (LNAFF) {
                // combine the 4 bn-partials: statsP[row][bn] = {S, SS}
                const float4* sp = (const float4*)(stats + (size_t)row * 8);
                const float4 a = sp[0], b = sp[1];
                const float S  = a.x + a.z + b.x + b.z;
                const float SS = a.y + a.w + b.y + b.w;
                const float mu  = S * (1.f / D_MODEL);
                const float var = SS * (1.f / D_MODEL) - mu * mu;
                rin = rsqrtf(var + 1e-5f);
                rmu = rin * mu;
            }
            float s4 = 0.f, ss4 = 0.f;
#pragma unroll
            for (int nt = 0; nt < 4; nt++) {
                const int col = bn * 256 + wn * 64 + nt * 16 + lr;
                float v = acc[mt][nt][r];
                if (LNAFF) v = rin * v - rmu * cw[nt] + bv[nt];
                else       v = v + bv[nt];
                if (STATS) { s4 += v; ss4 += v * v; }
                if (ACT == ACT_SILU) v = v / (1.f + __expf(-v));
                if (OUTF32)
                    ((float*)Cv)[(size_t)row * N + col] = v;
                else
                    ((ushort_t*)Cv)[(size_t)row * N + col] = f2bf(v);
            }
            if (STATS) {
                // reduce over the 16-lane lr group (stays within quad)
#pragma unroll
                for (int m_ = 1; m_ < 16; m_ <<= 1) {
                    s4  += __shfl_xor(s4,  m_);
                    ss4 += __shfl_xor(ss4, m_);
                }
                if (lr == 0) {
                    smem[rowl * 8 + wn * 2 + 0] = s4;
                    smem[rowl * 8 + wn * 2 + 1] = ss4;
                }
            }
        }
    }
    if (STATS) {
        __syncthreads();
        if (tid < 256) {
            const float s  = smem[tid * 8 + 0] + smem[tid * 8 + 2] +
                             smem[tid * 8 + 4] + smem[tid * 8 + 6];
            const float q2 = smem[tid * 8 + 1] + smem[tid * 8 + 3] +
                             smem[tid * 8 + 5] + smem[tid * 8 + 7];
            const size_t rowg = (size_t)(bm * 256 + tid);
            *(float2*)(stats + rowg * 8 + bn * 2) = (float2){s, q2};
        }
    }
}

// ---------------------------------------------------------------------------
// bf16 GEMM — R2 128x128 structure (kept for the small 1024^3 Wf GEMM and as
// fallback when M % 256 != 0).
// ---------------------------------------------------------------------------
template <int ACT, int OUTF32, int BIASF>
__global__ __launch_bounds__(256) void gemm_bf16(
    const ushort_t* __restrict__ A,
    const ushort_t* __restrict__ Bt,
    const float* __restrict__ bias,
    void* __restrict__ Cv, int M)
{
    constexpr int K = 1024, N = 1024;
    __shared__ ushort_t As[128 * 32];
    __shared__ ushort_t Bs[128 * 32];

    const int tid  = threadIdx.x;
    const int lane = tid & 63;
    const int wave = tid >> 6;
    const int quad = lane >> 4;
    const int lr   = lane & 15;
    const int bm   = blockIdx.x;
    const int bn   = blockIdx.y;
    const int wm   = (wave >> 1) * 64;
    const int wn   = (wave & 1) * 64;

    f32x4 acc[4][4];
#pragma unroll
    for (int i = 0; i < 4; i++)
#pragma unroll
        for (int j = 0; j < 4; j++) acc[i][j] = (f32x4){0.f, 0.f, 0.f, 0.f};

    int ci0 = tid, ci1 = tid + 256;
    int am0 = ci0 >> 2, akc0 = (ci0 & 3) ^ ((am0 >> 1) & 3);
    int am1 = ci1 >> 2, akc1 = (ci1 & 3) ^ ((am1 >> 1) & 3);
    const ushort_t* Ab = A + (size_t)(bm * 128) * K;
    const ushort_t* Bb = Bt + (size_t)(bn * 128) * K;

    for (int k0 = 0; k0 < K; k0 += 32) {
        GL2LDS(Ab + (size_t)am0 * K + k0 + akc0 * 8, As + ci0 * 8);
        GL2LDS(Ab + (size_t)am1 * K + k0 + akc1 * 8, As + ci1 * 8);
        GL2LDS(Bb + (size_t)am0 * K + k0 + akc0 * 8, Bs + ci0 * 8);
        GL2LDS(Bb + (size_t)am1 * K + k0 + akc1 * 8, Bs + ci1 * 8);
        __syncthreads();

        short8 af[4], bfr[4];
#pragma unroll
        for (int t = 0; t < 4; t++) {
            int m = wm + t * 16 + lr;
            af[t] = *(const short8*)(As + m * 32 + ((quad ^ ((m >> 1) & 3)) * 8));
            int n = wn + t * 16 + lr;
            bfr[t] = *(const short8*)(Bs + n * 32 + ((quad ^ ((n >> 1) & 3)) * 8));
        }
#pragma unroll
        for (int mt = 0; mt < 4; mt++)
#pragma unroll
            for (int nt = 0; nt < 4; nt++)
                acc[mt][nt] = __builtin_amdgcn_mfma_f32_16x16x32_bf16(
                    af[mt], bfr[nt], acc[mt][nt], 0, 0, 0);
        __syncthreads();
    }

    float bv[4];
#pragma unroll
    for (int nt = 0; nt < 4; nt++)
        bv[nt] = BIASF ? bias[bn * 128 + wn + nt * 16 + lr] : 0.f;

#pragma unroll
    for (int mt = 0; mt < 4; mt++) {
#pragma unroll
        for (int nt = 0; nt < 4; nt++) {
            const int col = bn * 128 + wn + nt * 16 + lr;
#pragma unroll
            for (int r = 0; r < 4; r++) {
                const int row = bm * 128 + wm + mt * 16 + quad * 4 + r;
                float v = acc[mt][nt][r] + bv[nt];
                if (ACT == ACT_SILU) v = v / (1.f + __expf(-v));
                if (OUTF32)
                    ((float*)Cv)[(size_t)row * N + col] = v;
                else
                    ((ushort_t*)Cv)[(size_t)row * N + col] = f2bf(v);
            }
        }
    }
}

// ---------------------------------------------------------------------------
// In-place LayerNorm over bf16 rows of 1024 (fallback path only).
// ---------------------------------------------------------------------------
__global__ __launch_bounds__(256) void layernorm_bf16(ushort_t* __restrict__ X)
{
    const int row = blockIdx.x;
    const int tid = threadIdx.x;
    ushort_t* x = X + (size_t)row * D_MODEL + tid * 4;

    uint2 u = *(uint2*)x;
    float a = bf2f(u.x & 0xffff), b = bf2f(u.x >> 16);
    float c = bf2f(u.y & 0xffff), d = bf2f(u.y >> 16);
    float s = a + b + c + d;
    float ss = a * a + b * b + c * c + d * d;

#pragma unroll
    for (int off = 32; off > 0; off >>= 1) {
        s += __shfl_down(s, off);
        ss += __shfl_down(ss, off);
    }
    __shared__ float sbuf[4], ssbuf[4];
    const int wave = tid >> 6;
    if ((tid & 63) == 0) { sbuf[wave] = s; ssbuf[wave] = ss; }
    __syncthreads();
    const float S = sbuf[0] + sbuf[1] + sbuf[2] + sbuf[3];
    const float SS = ssbuf[0] + ssbuf[1] + ssbuf[2] + ssbuf[3];
    const float mu = S * (1.f / D_MODEL);
    const float var = SS * (1.f / D_MODEL) - mu * mu;
    const float r = rsqrtf(var + 1e-5f);

    a = (a - mu) * r; b = (b - mu) * r; c = (c - mu) * r; d = (d - mu) * r;
    u.x = (unsigned)f2bf(a) | ((unsigned)f2bf(b) << 16);
    u.y = (unsigned)f2bf(c) | ((unsigned)f2bf(d) << 16);
    *(uint2*)x = u;
}

// ---------------------------------------------------------------------------
// ONE prep dispatch (flattened 1-D grid):
//  [0,6144):      weight prep (transpose/convert), 6 z-slices
//  [6144,+nxblk): x fp32 -> bf16
//  then 32 blocks bias_compose, 32 blocks csw0 (colsum of mlp_w[0]).
//  (stats zeroing removed: partials are written unconditionally.)
// ---------------------------------------------------------------------------
__global__ __launch_bounds__(256) void prep_all(
    const float* __restrict__ wq, const float* __restrict__ mlp_w,
    const float* __restrict__ w_out, const float* __restrict__ x,
    const float* __restrict__ b3, const float* __restrict__ bout,
    ushort_t* __restrict__ wt, ushort_t* __restrict__ Q,
    float* __restrict__ bf, float* __restrict__ csw, int nxblk)
{
    const int blk = blockIdx.x;
    const int tid = threadIdx.x;

    if (blk < 6144) {                    // ---- weight prep ----
        const int z = blk >> 10;
        const int t = blk & 1023;        // 32x32 tile index
        const int k0 = (t >> 5) * 32;
        const int n0 = (t & 31) * 32;
        const int r = tid >> 5;          // 0..7
        const int c = tid & 31;          // 0..31

        if (z == 5) {                    // plain convert W3
            const float* src = mlp_w + (size_t)3 * DD;
            ushort_t* dst = wt + (size_t)5 * DD;
#pragma unroll
            for (int i = 0; i < 4; i++) {
                size_t idx = (size_t)(k0 + r + 8 * i) * D_MODEL + n0 + c;
                dst[idx] = f2bf(src[idx]);
            }
            return;
        }
        const float* src = (z == 0) ? wq : (z < 4) ? (mlp_w + (size_t)(z - 1) * DD) : w_out;
        ushort_t* dst = wt + (size_t)z * DD;
        __shared__ float tile[32][33];
#pragma unroll
        for (int i = 0; i < 4; i++)
            tile[r + 8 * i][c] = src[(size_t)(k0 + r + 8 * i) * D_MODEL + n0 + c];
        __syncthreads();
#pragma unroll
        for (int i = 0; i < 4; i++)
            dst[(size_t)(n0 + r + 8 * i) * D_MODEL + k0 + c] = f2bf(tile[c][r + 8 * i]);
        return;
    }
    if (blk < 6144 + nxblk) {            // ---- x -> bf16 ----
        int i = (blk - 6144) * 256 + tid;
        const float4* p = (const float4*)(x + (size_t)i * 8);
        float4 v0 = p[0], v1 = p[1];
        union { ushort_t u[8]; uint4 v; } pk;
        pk.u[0] = f2bf(v0.x); pk.u[1] = f2bf(v0.y);
        pk.u[2] = f2bf(v0.z); pk.u[3] = f2bf(v0.w);
        pk.u[4] = f2bf(v1.x); pk.u[5] = f2bf(v1.y);
        pk.u[6] = f2bf(v1.z); pk.u[7] = f2bf(v1.w);
        *(uint4*)(Q + (size_t)i * 8) = pk.v;
        return;
    }
    const int t = blk - 6144 - nxblk;
    if (t < 32) {
        // ---- bias_compose: bf[n] = b3 @ Wout + bout, split-K 8-way ----
        const int n = t * 32 + (tid & 31);
        const int kg = tid >> 5;                 // 0..7
        float s = 0.f;
        for (int k = kg * 128; k < (kg + 1) * 128; k++)
            s = fmaf(b3[k], w_out[(size_t)k * D_MODEL + n], s);
        __shared__ float red[8][32];
        red[kg][tid & 31] = s;
        __syncthreads();
        if (kg == 0) {
            float tt = 0.f;
#pragma unroll
            for (int j = 0; j < 8; j++) tt += red[j][tid & 31];
            bf[n] = tt + bout[n];
        }
        return;
    }
    {
        // ---- csw0[n] = colsum of mlp_w[0], split-K 8-way ----
        const int b = t - 32;
        const int n = b * 32 + (tid & 31);
        const int kg = tid >> 5;
        float s = 0.f;
        for (int k = kg * 128; k < (kg + 1) * 128; k++)
            s += mlp_w[(size_t)k * D_MODEL + n];
        __shared__ float red2[8][32];
        red2[kg][tid & 31] = s;
        __syncthreads();
        if (kg == 0) {
            float tt = 0.f;
#pragma unroll
            for (int j = 0; j < 8; j++) tt += red2[j][tid & 31];
            csw[n] = tt;
        }
    }
}

// ---------------------------------------------------------------------------
extern "C" void kernel_launch(void* const* d_in, const int* in_sizes, int n_in,
                              void* d_out, int out_size, void* d_ws, size_t ws_size,
                              hipStream_t stream)
{
    const float* x     = (const float*)d_in[0];
    const float* wq    = (const float*)d_in[1];
    const float* bq    = (const float*)d_in[2];
    const float* mlp_w = (const float*)d_in[3];
    const float* mlp_b = (const float*)d_in[4];
    const float* w_out = (const float*)d_in[5];
    const float* b_out = (const float*)d_in[6];

    const int D = D_MODEL;
    const int M = in_sizes[0] / D;   // 16384

    // ws layout (ushort units) — IDENTICAL footprint to R1-R4 passing rounds:
    // wt[0..5)=transposed weights | [5DD,6DD)=W3 plain | [6DD,7DD)=WfT
    // | Q (M*D) | bf (1024 f32)
    ushort_t* wt    = (ushort_t*)d_ws;
    ushort_t* w3b   = wt + (size_t)5 * DD;
    ushort_t* wtF   = wt + (size_t)6 * DD;
    ushort_t* Q     = wt + (size_t)7 * DD;
    float*    bf    = (float*)(Q + (size_t)M * D);
    ushort_t* P     = (ushort_t*)d_out;   // bf16 acts alias d_out LOWER half
    // statsP (M x 8 f32 = 512KB) + csw (1024 f32) live in d_out's UPPER half
    // (bytes [32MB,64MB)) — dead until the final GEMM overwrites all of d_out.
    float*    ob    = (float*)d_out;
    float*    stats = ob + (size_t)M * D / 2;          // float offset 8M
    float*    csw   = stats + 8 * (size_t)M;

    // 1. all prep in one dispatch (+csw colsum; no stats zeroing needed)
    const int nxblk = M * D / 2048;     // x-convert blocks (8 elems/thread)
    prep_all<<<6144 + nxblk + 64, 256, 0, stream>>>(
        wq, mlp_w, w_out, x, mlp_b + 3 * D, b_out, wt, Q, bf, csw, nxblk);
    // 2. Wf^T = Wout^T @ W3^T  (N-major rep of Wf = W3*Wout) — small GEMM
    gemm_bf16<ACT_NONE, 0, 0><<<dim3(8, 8), 256, 0, stream>>>(
        wt + (size_t)4 * DD, w3b, nullptr, wtF, 1024);

    if ((M & 255) == 0) {
        dim3 grid(M / 256, D / 256);    // 64 x 4 = 256 blocks = 1/CU
        // 3. q = x @ wq + bq -> P (raw) + per-(row,bn) stats partials
        gemm256<ACT_NONE, 0, 1, 1, 0><<<grid, 512, 0, stream>>>(
            Q, wt + (size_t)0 * DD, bq, P, M, stats, nullptr);
        // 4. layer0 fused with LN-affine:  h0 = silu(r*(q@W0) - r*mu*csW0 + b0)
        gemm256<ACT_SILU, 0, 1, 0, 1><<<grid, 512, 0, stream>>>(
            P, wt + (size_t)1 * DD, mlp_b + 0 * D, Q, M, stats, csw);
        // 5-6. MLP layers 1..2 with SiLU (unchanged controls)
        gemm256<ACT_SILU, 0, 1, 0, 0><<<grid, 512, 0, stream>>>(
            Q, wt + (size_t)2 * DD, mlp_b + 1 * D, P, M, nullptr, nullptr);
        gemm256<ACT_SILU, 0, 1, 0, 0><<<grid, 512, 0, stream>>>(
            P, wt + (size_t)3 * DD, mlp_b + 2 * D, Q, M, nullptr, nullptr);
        // 7. fused (layer3 + out proj): out = h3 @ Wf + bf -> d_out fp32
        //    (reads Q in ws; overwrites P and the stats scratch — both dead)
        gemm256<ACT_NONE, 1, 1, 0, 0><<<grid, 512, 0, stream>>>(
            Q, wtF, bf, d_out, M, nullptr, nullptr);
    } else {
        dim3 grid(M / 128, D / 128);
        gemm_bf16<ACT_NONE, 0, 1><<<grid, 256, 0, stream>>>(Q, wt + (size_t)0 * DD, bq, P, M);
        layernorm_bf16<<<M, 256, 0, stream>>>(P);
        gemm_bf16<ACT_SILU, 0, 1><<<grid, 256, 0, stream>>>(P, wt + (size_t)1 * DD, mlp_b + 0 * D, Q, M);
        gemm_bf16<ACT_SILU, 0, 1><<<grid, 256, 0, stream>>>(Q, wt + (size_t)2 * DD, mlp_b + 1 * D, P, M);
        gemm_bf16<ACT_SILU, 0, 1><<<grid, 256, 0, stream>>>(P, wt + (size_t)3 * DD, mlp_b + 2 * D, Q, M);
        gemm_bf16<ACT_NONE, 1, 1><<<grid, 256, 0, stream>>>(Q, wtF, bf, d_out, M);
    }
}